// Round 8
// baseline (432.765 us; speedup 1.0000x reference)
//
#include <hip/hip_runtime.h>

// Problem constants (fixed by setup_inputs)
#define BB 4
#define HH 256
#define WW 512
#define LL 21
#define PIX (BB*HH*WW)            // 524288 pixels
#define MSL 24                    // uint8 labels per pixel (24 B rows)
#define TSL 24                    // fp16 labels per pixel  (48 B rows)
#define MFLD ((size_t)PIX*MSL)    // bytes per direction's msg field
#define PADV 1000.0f              // pad-label value: self-sanitizing (never min)

// Chunked scanlines, HA=32-pixel m=0 warm-up halo (not stored).
// Horizontal (S=512): CH=128 -> 4 chunks x 2048 lines = 8192 cl -> 1024 blocks.
// Vertical   (S=256): CHV=64 -> 4 chunks x 4096 lines = 16384 cl -> 2048 blocks.
// Blocks interleaved hz,vt,vt so every CU gets the 1:2 duration mix.
#define CH 128
#define CHV 64
#define HA 32
#define FDV 16                    // vt FIFO: 32 loads + 16 stores = 48 <= 63
#define HB 8                      // horizontal batch steps (LDS-staged)

typedef float    fvec4 __attribute__((ext_vector_type(4)));
typedef _Float16 hvec4 __attribute__((ext_vector_type(4)));
typedef _Float16 hvec8 __attribute__((ext_vector_type(8)));
typedef unsigned uvec4 __attribute__((ext_vector_type(4)));

__device__ __forceinline__ fvec4 load4u(const float* p) {
    fvec4 v; __builtin_memcpy(&v, p, 16); return v;
}
__device__ __forceinline__ void store4u(float* p, fvec4 v) {
    __builtin_memcpy(p, &v, 16);
}

// ---------------------------------------------------------------------------
// pad: tot = phi, fp16 padded-24 (pads = PADV). One pixel per thread.
// ---------------------------------------------------------------------------
__global__ __launch_bounds__(256) void pad_kernel(
    const float* __restrict__ phi, _Float16* __restrict__ tot)
{
    int p = blockIdx.x * 256 + threadIdx.x;      // < PIX
    const float* pp = phi + (size_t)p * LL;
    float r[24];
    fvec4 u0 = load4u(pp + 0), u1 = load4u(pp + 4), u2 = load4u(pp + 8);
    fvec4 u3 = load4u(pp + 12), u4 = load4u(pp + 16);
    #pragma unroll
    for (int e = 0; e < 4; ++e) {
        r[e] = u0[e]; r[4+e] = u1[e]; r[8+e] = u2[e];
        r[12+e] = u3[e]; r[16+e] = u4[e];
    }
    r[20] = pp[20];
    r[21] = r[22] = r[23] = PADV;

    _Float16* op = tot + (size_t)p * TSL;
    #pragma unroll
    for (int c3 = 0; c3 < 3; ++c3) {
        hvec8 h;
        #pragma unroll
        for (int e = 0; e < 8; ++e) h[e] = (_Float16)r[8*c3 + e];
        *(hvec8*)(op + 8*c3) = h;
    }
}

// ---------------------------------------------------------------------------
// Elementwise: r = phi*scale + sum_d decode(msg_d).
// padded_out=1 -> fp16 padded-24 tot scratch (pads = PADV); 0 -> packed fp32.
// ---------------------------------------------------------------------------
__global__ __launch_bounds__(256) void ewise_kernel(
    const float* __restrict__ phi, const unsigned char* __restrict__ msgs,
    const float* __restrict__ scales,
    float* __restrict__ outf, _Float16* __restrict__ outh,
    float scale, int padded_out)
{
    int p = blockIdx.x * 256 + threadIdx.x;      // < PIX
    const float* pp = phi + (size_t)p * LL;

    float r[24];
    {
        fvec4 u0 = load4u(pp + 0), u1 = load4u(pp + 4), u2 = load4u(pp + 8);
        fvec4 u3 = load4u(pp + 12), u4 = load4u(pp + 16);
        #pragma unroll
        for (int e = 0; e < 4; ++e) {
            r[e]      = u0[e] * scale;
            r[4 + e]  = u1[e] * scale;
            r[8 + e]  = u2[e] * scale;
            r[12 + e] = u3[e] * scale;
            r[16 + e] = u4[e] * scale;
        }
        r[20] = pp[20] * scale;
        r[21] = r[22] = r[23] = 0.f;
    }

    fvec4 sc = load4u(scales);                   // per-dir ranges R

    #pragma unroll
    for (int d = 0; d < 4; ++d) {
        const unsigned* mp =
            (const unsigned*)(msgs + (size_t)d * MFLD + (size_t)p * MSL);
        uint2 w0 = *(const uint2*)(mp + 0);      // rows are 8-B aligned
        uint2 w1 = *(const uint2*)(mp + 2);
        uint2 w2 = *(const uint2*)(mp + 4);
        unsigned w[6] = { w0.x, w0.y, w1.x, w1.y, w2.x, w2.y };
        float rs = sc[d] * (1.f / 255.f);
        #pragma unroll
        for (int j = 0; j < 21; ++j)
            r[j] += (float)((w[j >> 2] >> ((j & 3) * 8)) & 0xffu) * rs;
    }

    if (padded_out) {
        _Float16* op = outh + (size_t)p * TSL;
        r[21] = r[22] = r[23] = PADV;
        #pragma unroll
        for (int c3 = 0; c3 < 3; ++c3) {
            hvec8 h;
            #pragma unroll
            for (int e = 0; e < 8; ++e) h[e] = (_Float16)r[8*c3 + e];
            *(hvec8*)(op + 8*c3) = h;
        }
    } else {
        float* op = outf + (size_t)p * LL;
        store4u(op + 0,  *(const fvec4*)(r + 0));
        store4u(op + 4,  *(const fvec4*)(r + 4));
        store4u(op + 8,  *(const fvec4*)(r + 8));
        store4u(op + 12, *(const fvec4*)(r + 12));
        store4u(op + 16, *(const fvec4*)(r + 16));
        op[20] = r[20];
    }
}

// ---------------------------------------------------------------------------
// 8-lane-group min/max (broadcast to all 8 lanes), pure DPP — no DS pipe.
// ---------------------------------------------------------------------------
__device__ __forceinline__ float min8(float x)
{
    int xi = __float_as_int(x); int y;
    y = __builtin_amdgcn_update_dpp(xi, xi, 0xB1, 0xf, 0xf, false);
    x = fminf(x, __int_as_float(y)); xi = __float_as_int(x);
    y = __builtin_amdgcn_update_dpp(xi, xi, 0x4E, 0xf, 0xf, false);
    x = fminf(x, __int_as_float(y)); xi = __float_as_int(x);
    y = __builtin_amdgcn_update_dpp(xi, xi, 0x141, 0xf, 0xf, false);
    x = fminf(x, __int_as_float(y));
    return x;
}
__device__ __forceinline__ float max8(float x)
{
    int xi = __float_as_int(x); int y;
    y = __builtin_amdgcn_update_dpp(xi, xi, 0xB1, 0xf, 0xf, false);
    x = fmaxf(x, __int_as_float(y)); xi = __float_as_int(x);
    y = __builtin_amdgcn_update_dpp(xi, xi, 0x4E, 0xf, 0xf, false);
    x = fmaxf(x, __int_as_float(y)); xi = __float_as_int(x);
    y = __builtin_amdgcn_update_dpp(xi, xi, 0x141, 0xf, 0xf, false);
    x = fmaxf(x, __int_as_float(y));
    return x;
}

// ---------------------------------------------------------------------------
// Directional sweep. One chunk-line per 8-lane group; d, chunk block-uniform.
// blockIdx interleaved 1 hz : 2 vt (CU-level duration balance, R7 postmortem:
// per-wave duty 19% and CUs drawing all-vt slots idled in the tail).
//
// hz: LDS-staged dense batches + REGISTER-double-buffered th8/wd8 so each
//     batch's first step doesn't eat the ds_read latency.
// vt: register FIFO, FDV=16 (R7-proven).
// Pad labels carry PADV (=1000): no per-step sanitize needed — pads never win
// a min, dummy lanes duplicate lane 0, pad msgs quantize to 255 and decode
// back to ~c, keeping T_pad ~ PADV forever.
//
// Potts fast path (unnormalized, exact):
//   Tmin_s = min_l T_s(l);  Q_s = Tmin_s + c
//   T_{s+1}(l) = u_{s+1}(l) + min(T_s(l), Q_s)
//   m_{s+1}(l) = min(T_s(l), Q_s) - Tmin_s          (m_0 = 0)
// ---------------------------------------------------------------------------
template<bool FIRST>
__global__ __launch_bounds__(64) void sweep_kernel(
    const _Float16* __restrict__ tot, const float* __restrict__ ctx,
    unsigned char* __restrict__ msgs, float* __restrict__ scales)
{
    // one pool, two overlays (potts-staging vs general path; never both live)
    __shared__ __align__(16) unsigned char pool[11648];
    auto ltot = (unsigned char (*)[8][416])pool;            // [2][8][416] 6656
    auto lmsg = (unsigned char (*)[8][208])(pool + 6656);   // [2][8][208] 3328
    auto lout = (unsigned char (*)[208])(pool + 9984);      // [8][208]    1664
    float* shc  = (float*)pool;                             // 441 f  (general)
    float* shrm = (float*)(pool + 1792);                    // 21 f   (general)
    auto   sht  = (float (*)[24])(pool + 1920);             // 8x24 f (general)

    const int lane = threadIdx.x;
    const int g = lane >> 3, k = lane & 7;

    // interleave: block 3t -> hz t; blocks 3t+1,3t+2 -> vt 2t, 2t+1
    const int b3 = blockIdx.x / 3;
    const int r3 = blockIdx.x - 3 * b3;
    const bool hz = (r3 == 0);

    int d, chunk, r;                 // r = line index (row for hz, col-id for v)
    int tstr, mstr;                  // per-step strides (elements / bytes)
    size_t pbase;                    // first-pixel index of the full line
    if (hz) {
        int cl = b3 * 8 + g;                 // [0, 8192)
        chunk = cl >> 11;                    // 0..3  (2048 lines/chunk, %8==0)
        int line = cl & 2047;
        d = line >> 10;                      // 0 or 1
        r = line & 1023;                     // b*H + h
        pbase = (size_t)r * WW;
        tstr = TSL; mstr = MSL;
        if (d == 1) { pbase += WW - 1; tstr = -tstr; mstr = -mstr; }
    } else {
        int vb = 2 * b3 + (r3 - 1);            // [0, 2048)
        int cl = vb * 8 + g;                   // [0, 16384)
        chunk = cl >> 12;                    // 0..3  (4096 lines/chunk, %8==0)
        int line = cl & 4095;
        d = 2 + (line >> 11);                // 2 or 3
        r = line & 2047;
        int bb = r >> 9, w = r & 511;
        pbase = (size_t)bb * HH * WW + w;
        tstr = WW * TSL; mstr = WW * MSL;
        if (d == 3) { pbase += (size_t)(HH - 1) * WW; tstr = -tstr; mstr = -mstr; }
    }
    const int CL = hz ? CH : CHV;                        // chunk length
    const int ss = (chunk == 0) ? 0 : HA;                // halo steps
    const int sw = (chunk == 0) ? 0 : chunk * CL - HA;   // start (sweep order)

    const float* ctxd = ctx + d * (LL * LL);
    const float  c    = ctxd[1];          // candidate Potts constant

    // Potts detection + ctx range (lane k scans its columns 4k..4k+3)
    bool bad = (c < 0.f);
    float cmx = -1e30f, cmn = 1e30f;
    #pragma unroll
    for (int e = 0; e < 4; ++e) {
        int j = 4 * k + e;
        if (j < LL) {
            for (int l = 0; l < LL; ++l) {
                float v = ctxd[l * LL + j];
                float want = (l == j) ? 0.f : c;
                if (v != want) bad = true;
                cmx = fmaxf(cmx, v); cmn = fminf(cmn, v);
            }
        }
    }
    const bool potts = (__ballot(bad) == 0ull);
    const float R    = fmaxf(max8(cmx) - min8(cmn), 0.f);
    const float s255 = (R > 0.f) ? 255.f / R : 0.f;
    const float rs   = R * (1.f / 255.f);

    if (FIRST && lane == 0) scales[d] = R;   // same value from every block

    const bool act = (k < 6);
    const int  koff = act ? 4 * k : 0;    // dummies alias lane-0 addresses
    const bool dpos = ((d & 1) == 0);

    if (potts && hz) {
        // ================= horizontal: LDS-staged dense batches ============
        const int r0 = r - g;                       // block's first row
        const int sl = lane & 7;                    // staging line index
        const int lg = lane >> 3;                   // staging granule index
        const char* tlineb = (const char*)tot
                             + (size_t)(r0 + sl) * ((size_t)WW * 48);
        unsigned char* mlineb = msgs + (size_t)d * MFLD
                              + (size_t)(r0 + sl) * ((size_t)WW * 24);

        const int NB  = (ss + CH) / HB;             // 16 or 20 batches
        const int swb = ss / HB;                    // first stored batch

        // staging registers (dense 16-B granules; batch = 8 px/line)
        uvec4 rt0, rt1, rt2;                        // tot: 384 B/line
        uvec4 rm0; uint2 rm1;                       // msg: 192 B/line

        auto wpix = [&](int b) {                    // batch window base pixel
            return dpos ? (sw + HB * b) : ((WW - HB) - sw - HB * b);
        };
        auto issue = [&](int b) {                   // global -> regs (dense)
            int wp = wpix(b);
            const char* tb = tlineb + (size_t)wp * 48;
            rt0 = *(const uvec4*)(tb + lg * 16);
            rt1 = *(const uvec4*)(tb + 128 + lg * 16);
            rt2 = *(const uvec4*)(tb + 256 + lg * 16);
            if (!FIRST) {
                const unsigned char* mq = mlineb + (size_t)wp * 24;
                rm0 = *(const uvec4*)(mq + lg * 16);
                rm1 = *(const uint2*)(mq + 128 + lg * 8);
            }
        };
        auto commit = [&](int b) {                  // regs -> LDS buf (b&1)
            unsigned char* Lt = &ltot[b & 1][sl][0];
            *(uvec4*)(Lt + lg * 16)       = rt0;
            *(uvec4*)(Lt + 128 + lg * 16) = rt1;
            *(uvec4*)(Lt + 256 + lg * 16) = rt2;
            if (!FIRST) {
                unsigned char* Lm = &lmsg[b & 1][sl][0];
                *(uvec4*)(Lm + lg * 16)      = rm0;
                *(uint2*)(Lm + 128 + lg * 8) = rm1;
            }
        };
        auto flushb = [&](int b) {                  // LDS out -> global (dense)
            int wp = wpix(b);
            unsigned char* mq = mlineb + (size_t)wp * 24;
            const unsigned char* Lo = &lout[sl][0];
            uvec4 a = *(const uvec4*)(Lo + lg * 16);
            uint2 bq = *(const uint2*)(Lo + 128 + lg * 8);
            *(uvec4*)(mq + lg * 16)      = a;
            *(uint2*)(mq + 128 + lg * 8) = bq;
        };
        // register window load from LDS buf (b&1)
        auto loadw = [&](int b, hvec4* th8, unsigned* wd8) {
            const unsigned char* Lt = &ltot[b & 1][g][0];
            const unsigned char* Lm = &lmsg[b & 1][g][0];
            #pragma unroll
            for (int i = 0; i < HB; ++i) {
                int p = dpos ? i : HB - 1 - i;
                th8[i] = *(const hvec4*)(Lt + p * 48 + 2 * koff);
                wd8[i] = FIRST ? 0u : *(const unsigned*)(Lm + p * 24 + koff);
            }
        };

        float mn0 = 0.f, mn1 = 0.f, mn2 = 0.f, mn3 = 0.f, tminp = 0.f;

        hvec4 thA[HB], thB[HB]; unsigned wdA[HB], wdB[HB];

        issue(0); commit(0);
        loadw(0, thA, wdA);
        issue(1);
        for (int b = 0; b < NB; ++b) {
            const bool st = (b >= swb);
            const bool evn = ((b & 1) == 0);
            hvec4* thc = evn ? thA : thB; unsigned* wdc = evn ? wdA : wdB;
            hvec4* thn = evn ? thB : thA; unsigned* wdn = evn ? wdB : wdA;

            if (b + 1 < NB) {
                commit(b + 1);                 // LDS write (from regs)
                loadw(b + 1, thn, wdn);        // prefetch next window to regs
            }
            if (b + 2 < NB) issue(b + 2);

            #pragma unroll
            for (int i = 0; i < HB; ++i) {
                int p = dpos ? i : HB - 1 - i;
                // quantize state BEFORE consuming this pixel (side ops)
                if (st && act) {
                    float off = fmaf(-tminp, s255, 0.5f);
                    unsigned q0 = (unsigned)fmaf(mn0, s255, off);
                    unsigned q1 = (unsigned)fmaf(mn1, s255, off);
                    unsigned q2 = (unsigned)fmaf(mn2, s255, off);
                    unsigned q3 = (unsigned)fmaf(mn3, s255, off);
                    *(unsigned*)(&lout[g][0] + p * 24 + 4 * k) =
                        q0 | (q1 << 8) | (q2 << 16) | (q3 << 24);
                }
                hvec4 th = thc[i]; unsigned wd = wdc[i];
                float T0, T1, T2, T3;
                if (FIRST) {
                    T0 = (float)th[0] + mn0; T1 = (float)th[1] + mn1;
                    T2 = (float)th[2] + mn2; T3 = (float)th[3] + mn3;
                } else {
                    T0 = fmaf(-rs, (float)( wd        & 0xffu), (float)th[0]) + mn0;
                    T1 = fmaf(-rs, (float)((wd >>  8) & 0xffu), (float)th[1]) + mn1;
                    T2 = fmaf(-rs, (float)((wd >> 16) & 0xffu), (float)th[2]) + mn2;
                    T3 = fmaf(-rs, (float)( wd >> 24        ), (float)th[3]) + mn3;
                }
                float lm = fminf(fminf(T0, T1), fminf(T2, T3));
                lm = min8(lm);
                float Q = lm + c;
                mn0 = fminf(T0, Q); mn1 = fminf(T1, Q);
                mn2 = fminf(T2, Q); mn3 = fminf(T3, Q);
                tminp = lm;
            }
            if (st) flushb(b);
        }
    } else if (potts) {
        // ================= vertical: register FIFO (FDV=16) ================
        const _Float16* tp = tot + pbase * TSL + koff + (ptrdiff_t)sw * tstr;
        unsigned char*  mb = msgs + (size_t)d * MFLD + pbase * MSL + koff
                                  + (ptrdiff_t)sw * mstr;

        hvec4 tf[FDV]; unsigned mfq[FDV];
        #pragma unroll
        for (int i = 0; i < FDV; ++i) {
            tf[i] = *(const hvec4*)(tp + (ptrdiff_t)i * tstr);
            mfq[i] = FIRST ? 0u : *(const unsigned*)(mb + (ptrdiff_t)i * mstr);
        }
        const _Float16* tld = tp + (ptrdiff_t)FDV * tstr;
        const unsigned char* mld = mb + (ptrdiff_t)FDV * mstr;
        unsigned char* mst = mb;

        float mn0 = 0.f, mn1 = 0.f, mn2 = 0.f, mn3 = 0.f, tminp = 0.f;

        auto vstep = [&](hvec4 th, unsigned wd, bool st) {
            if (st && act) {
                float off = fmaf(-tminp, s255, 0.5f);
                unsigned q0 = (unsigned)fmaf(mn0, s255, off);
                unsigned q1 = (unsigned)fmaf(mn1, s255, off);
                unsigned q2 = (unsigned)fmaf(mn2, s255, off);
                unsigned q3 = (unsigned)fmaf(mn3, s255, off);
                *(unsigned*)mst = q0 | (q1 << 8) | (q2 << 16) | (q3 << 24);
            }
            mst += mstr;
            float T0, T1, T2, T3;
            if (FIRST) {
                T0 = (float)th[0] + mn0; T1 = (float)th[1] + mn1;
                T2 = (float)th[2] + mn2; T3 = (float)th[3] + mn3;
            } else {
                T0 = fmaf(-rs, (float)( wd        & 0xffu), (float)th[0]) + mn0;
                T1 = fmaf(-rs, (float)((wd >>  8) & 0xffu), (float)th[1]) + mn1;
                T2 = fmaf(-rs, (float)((wd >> 16) & 0xffu), (float)th[2]) + mn2;
                T3 = fmaf(-rs, (float)( wd >> 24        ), (float)th[3]) + mn3;
            }
            float lm = fminf(fminf(T0, T1), fminf(T2, T3));
            lm = min8(lm);
            float Q = lm + c;
            mn0 = fminf(T0, Q); mn1 = fminf(T1, Q);
            mn2 = fminf(T2, Q); mn3 = fminf(T3, Q);
            tminp = lm;
        };

        const int nout = (ss + CHV - FDV) / FDV;     // 3 or 5
        for (int j = 0; j < nout; ++j) {
            const bool st = (FDV * j >= ss);
            #pragma unroll
            for (int i = 0; i < FDV; ++i) {
                hvec4 th = tf[i]; unsigned wd = mfq[i];
                tf[i] = *(const hvec4*)tld;
                if (!FIRST) mfq[i] = *(const unsigned*)mld;
                tld += tstr; mld += mstr;
                vstep(th, wd, st);
            }
        }
        #pragma unroll
        for (int i = 0; i < FDV; ++i) vstep(tf[i], mfq[i], true);
    } else {
        // ========== general min-plus path (arbitrary ctx; cold) ============
        for (int i = lane; i < LL * LL; i += 64) shc[i] = ctxd[i];
        __syncthreads();
        if (lane < LL) {
            float mn = shc[lane * LL];
            for (int j = 1; j < LL; ++j) mn = fminf(mn, shc[lane * LL + j]);
            shrm[lane] = mn;
        }
        __syncthreads();

        const bool okA = (k < 6);
        const bool okB = (k < 5);
        const _Float16* tp = tot + pbase * TSL + koff + (ptrdiff_t)sw * tstr;
        const unsigned char* mld = msgs + (size_t)d * MFLD + pbase * MSL + koff
                                        + (ptrdiff_t)sw * mstr;
        unsigned char* mst = (unsigned char*)mld;

        float m0 = 0.f, m1 = 0.f, m2 = 0.f, m3 = 0.f;
        const int j0 = (4 * k     < LL) ? 4 * k     : LL - 1;
        const int j1 = (4 * k + 1 < LL) ? 4 * k + 1 : LL - 1;
        const int j2 = (4 * k + 2 < LL) ? 4 * k + 2 : LL - 1;
        const int j3 = (4 * k + 3 < LL) ? 4 * k + 3 : LL - 1;

        const int total = ss + CL;
        for (int t = 0; t < total; ++t) {
            const bool st = (t >= ss);
            if (st && act) {
                unsigned q0 = (unsigned)fminf(fmaf(m0, s255, 0.5f), 255.f);
                unsigned q1 = (unsigned)fminf(fmaf(m1, s255, 0.5f), 255.f);
                unsigned q2 = (unsigned)fminf(fmaf(m2, s255, 0.5f), 255.f);
                unsigned q3 = (unsigned)fminf(fmaf(m3, s255, 0.5f), 255.f);
                *(unsigned*)mst = q0 | (q1 << 8) | (q2 << 16) | (q3 << 24);
            }
            hvec4 th = *(const hvec4*)(tp + (ptrdiff_t)t * tstr);
            unsigned wd = FIRST ? 0u
                : *(const unsigned*)(mld + (ptrdiff_t)t * mstr);
            mst += mstr;
            float t0, t1, t2, t3;
            if (FIRST) {
                t0 = (float)th[0] + m0; t1 = (float)th[1] + m1;
                t2 = (float)th[2] + m2; t3 = (float)th[3] + m3;
            } else {
                t0 = fmaf(-rs, (float)( wd        & 0xffu), (float)th[0]) + m0;
                t1 = fmaf(-rs, (float)((wd >>  8) & 0xffu), (float)th[1]) + m1;
                t2 = fmaf(-rs, (float)((wd >> 16) & 0xffu), (float)th[2]) + m2;
                t3 = fmaf(-rs, (float)( wd >> 24        ), (float)th[3]) + m3;
            }
            __syncthreads();
            if (okA) sht[g][4 * k] = t0;
            if (okB) {
                sht[g][4 * k + 1] = t1;
                sht[g][4 * k + 2] = t2;
                sht[g][4 * k + 3] = t3;
            }
            __syncthreads();
            float mnA = 1e30f, mnB = 1e30f, mnC = 1e30f, mnD = 1e30f;
            float gm  = 1e30f;
            for (int l = 0; l < LL; ++l) {
                float tl = sht[g][l];
                mnA = fminf(mnA, tl + shc[l * LL + j0]);
                mnB = fminf(mnB, tl + shc[l * LL + j1]);
                mnC = fminf(mnC, tl + shc[l * LL + j2]);
                mnD = fminf(mnD, tl + shc[l * LL + j3]);
                gm  = fminf(gm,  tl + shrm[l]);
            }
            m0 = mnA - gm; m1 = mnB - gm; m2 = mnC - gm; m3 = mnD - gm;
        }
    }
}

// ---------------------------------------------------------------------------
extern "C" void kernel_launch(void* const* d_in, const int* in_sizes, int n_in,
                              void* d_out, int out_size, void* d_ws, size_t ws_size,
                              hipStream_t stream)
{
    (void)in_sizes; (void)n_in; (void)out_size; (void)ws_size;

    const float* phi = (const float*)d_in[0];
    const float* ctx = (const float*)d_in[1];   // [4,21,21]
    float* out = (float*)d_out;                 // packed final output

    unsigned char* msgs = (unsigned char*)d_ws;            // 4 uint8 fields (50.3 MB)
    _Float16* totp = (_Float16*)((char*)d_ws + 4 * MFLD);  // fp16 tot (25.2 MB)
    float* scales  = (float*)((char*)totp + (size_t)PIX * TSL * sizeof(_Float16));

    const int EW_BLOCKS = PIX / 256;            // 2048, exact
    const int SW_BLOCKS = 1024 + 2048;          // hz + vt, interleaved 1:2

    // tot = phi (fp16 padded)
    pad_kernel<<<EW_BLOCKS, 256, 0, stream>>>(phi, totp);

    // iteration 1: old msgs == 0 (never read); writes scales[] for ewise
    sweep_kernel<true><<<SW_BLOCKS, 64, 0, stream>>>(totp, ctx, msgs, scales);

    for (int it = 1; it < 5; ++it) {
        ewise_kernel<<<EW_BLOCKS, 256, 0, stream>>>(phi, msgs, scales,
                                                    nullptr, totp, 1.0f, 1);
        sweep_kernel<false><<<SW_BLOCKS, 64, 0, stream>>>(totp, ctx, msgs, scales);
    }

    // final belief: phi*GAMMA_MNODE + sum of messages (packed fp32 to d_out)
    ewise_kernel<<<EW_BLOCKS, 256, 0, stream>>>(phi, msgs, scales,
                                                out, nullptr, 2.0f, 0);
}

// Round 10
// 409.426 us; speedup vs baseline: 1.0570x; 1.0570x over previous
//
#include <hip/hip_runtime.h>

// Problem constants (fixed by setup_inputs)
#define BB 4
#define HH 256
#define WW 512
#define LL 21
#define PIX (BB*HH*WW)            // 524288 pixels
#define MSL 24                    // uint8 labels per pixel (24 B rows)
#define TSL 24                    // fp16 labels per pixel  (48 B rows)
#define MFLD ((size_t)PIX*MSL)    // bytes per direction's msg field
#define PADV 1000.0f              // pad-label value: self-sanitizing (never min)

// Chunked scanlines, HA=32-pixel m=0 warm-up halo (not stored).
// Horizontal (S=512): CH=128 -> 4 chunks x 2048 lines = 8192 cl -> 1024 blocks.
// Vertical   (S=256): CHV=64 -> 4 chunks x 4096 lines = 16384 cl -> 2048 blocks.
// R9 post-mortem: CHV=32 + single-buffer LDS bundle FAILED (absmax 1.5);
// both reverted to the R7-proven geometry. PADV kept (validated in R8).
#define CH 128
#define CHV 64
#define HA 32
#define FDV 16                    // vt FIFO: 32 loads + 16 stores = 48 <= 63
#define HB 8                      // horizontal batch steps (LDS-staged)

typedef float    fvec4 __attribute__((ext_vector_type(4)));
typedef _Float16 hvec4 __attribute__((ext_vector_type(4)));
typedef _Float16 hvec8 __attribute__((ext_vector_type(8)));
typedef unsigned uvec4 __attribute__((ext_vector_type(4)));

__device__ __forceinline__ fvec4 load4u(const float* p) {
    fvec4 v; __builtin_memcpy(&v, p, 16); return v;
}
__device__ __forceinline__ void store4u(float* p, fvec4 v) {
    __builtin_memcpy(p, &v, 16);
}

// ---------------------------------------------------------------------------
// pad: tot = phi, fp16 padded-24 (pads = PADV). One pixel per thread.
// ---------------------------------------------------------------------------
__global__ __launch_bounds__(256) void pad_kernel(
    const float* __restrict__ phi, _Float16* __restrict__ tot)
{
    int p = blockIdx.x * 256 + threadIdx.x;      // < PIX
    const float* pp = phi + (size_t)p * LL;
    float r[24];
    fvec4 u0 = load4u(pp + 0), u1 = load4u(pp + 4), u2 = load4u(pp + 8);
    fvec4 u3 = load4u(pp + 12), u4 = load4u(pp + 16);
    #pragma unroll
    for (int e = 0; e < 4; ++e) {
        r[e] = u0[e]; r[4+e] = u1[e]; r[8+e] = u2[e];
        r[12+e] = u3[e]; r[16+e] = u4[e];
    }
    r[20] = pp[20];
    r[21] = r[22] = r[23] = PADV;

    _Float16* op = tot + (size_t)p * TSL;
    #pragma unroll
    for (int c3 = 0; c3 < 3; ++c3) {
        hvec8 h;
        #pragma unroll
        for (int e = 0; e < 8; ++e) h[e] = (_Float16)r[8*c3 + e];
        *(hvec8*)(op + 8*c3) = h;
    }
}

// ---------------------------------------------------------------------------
// Elementwise: r = phi*scale + sum_d decode(msg_d).
// padded_out=1 -> fp16 padded-24 tot scratch (pads = PADV); 0 -> packed fp32.
// ---------------------------------------------------------------------------
__global__ __launch_bounds__(256) void ewise_kernel(
    const float* __restrict__ phi, const unsigned char* __restrict__ msgs,
    const float* __restrict__ scales,
    float* __restrict__ outf, _Float16* __restrict__ outh,
    float scale, int padded_out)
{
    int p = blockIdx.x * 256 + threadIdx.x;      // < PIX
    const float* pp = phi + (size_t)p * LL;

    float r[24];
    {
        fvec4 u0 = load4u(pp + 0), u1 = load4u(pp + 4), u2 = load4u(pp + 8);
        fvec4 u3 = load4u(pp + 12), u4 = load4u(pp + 16);
        #pragma unroll
        for (int e = 0; e < 4; ++e) {
            r[e]      = u0[e] * scale;
            r[4 + e]  = u1[e] * scale;
            r[8 + e]  = u2[e] * scale;
            r[12 + e] = u3[e] * scale;
            r[16 + e] = u4[e] * scale;
        }
        r[20] = pp[20] * scale;
        r[21] = r[22] = r[23] = 0.f;
    }

    fvec4 sc = load4u(scales);                   // per-dir ranges R

    #pragma unroll
    for (int d = 0; d < 4; ++d) {
        const unsigned* mp =
            (const unsigned*)(msgs + (size_t)d * MFLD + (size_t)p * MSL);
        uint2 w0 = *(const uint2*)(mp + 0);      // rows are 8-B aligned
        uint2 w1 = *(const uint2*)(mp + 2);
        uint2 w2 = *(const uint2*)(mp + 4);
        unsigned w[6] = { w0.x, w0.y, w1.x, w1.y, w2.x, w2.y };
        float rs = sc[d] * (1.f / 255.f);
        #pragma unroll
        for (int j = 0; j < 21; ++j)
            r[j] += (float)((w[j >> 2] >> ((j & 3) * 8)) & 0xffu) * rs;
    }

    if (padded_out) {
        _Float16* op = outh + (size_t)p * TSL;
        r[21] = r[22] = r[23] = PADV;
        #pragma unroll
        for (int c3 = 0; c3 < 3; ++c3) {
            hvec8 h;
            #pragma unroll
            for (int e = 0; e < 8; ++e) h[e] = (_Float16)r[8*c3 + e];
            *(hvec8*)(op + 8*c3) = h;
        }
    } else {
        float* op = outf + (size_t)p * LL;
        store4u(op + 0,  *(const fvec4*)(r + 0));
        store4u(op + 4,  *(const fvec4*)(r + 4));
        store4u(op + 8,  *(const fvec4*)(r + 8));
        store4u(op + 12, *(const fvec4*)(r + 12));
        store4u(op + 16, *(const fvec4*)(r + 16));
        op[20] = r[20];
    }
}

// ---------------------------------------------------------------------------
// 8-lane-group min/max (broadcast to all 8 lanes), pure DPP — no DS pipe.
// ---------------------------------------------------------------------------
__device__ __forceinline__ float min8(float x)
{
    int xi = __float_as_int(x); int y;
    y = __builtin_amdgcn_update_dpp(xi, xi, 0xB1, 0xf, 0xf, false);
    x = fminf(x, __int_as_float(y)); xi = __float_as_int(x);
    y = __builtin_amdgcn_update_dpp(xi, xi, 0x4E, 0xf, 0xf, false);
    x = fminf(x, __int_as_float(y)); xi = __float_as_int(x);
    y = __builtin_amdgcn_update_dpp(xi, xi, 0x141, 0xf, 0xf, false);
    x = fminf(x, __int_as_float(y));
    return x;
}
__device__ __forceinline__ float max8(float x)
{
    int xi = __float_as_int(x); int y;
    y = __builtin_amdgcn_update_dpp(xi, xi, 0xB1, 0xf, 0xf, false);
    x = fmaxf(x, __int_as_float(y)); xi = __float_as_int(x);
    y = __builtin_amdgcn_update_dpp(xi, xi, 0x4E, 0xf, 0xf, false);
    x = fmaxf(x, __int_as_float(y)); xi = __float_as_int(x);
    y = __builtin_amdgcn_update_dpp(xi, xi, 0x141, 0xf, 0xf, false);
    x = fmaxf(x, __int_as_float(y));
    return x;
}

// ---------------------------------------------------------------------------
// Directional sweep. One chunk-line per 8-lane group; d, chunk block-uniform.
// blocks [0,1024): horizontal (d 0/1, CH=128); [1024,3072): vertical (d 2/3,
// CHV=64). Exactly the R7-proven structure; only the per-step pad sanitize
// is gone (PADV pads never win a min; validated in R8's passing run).
//
// hz: LDS double-buffered dense batches; per-batch th8/wd8 register hoist.
// vt: register FIFO, FDV=16 (48 outstanding vmem <= vmcnt window).
//
// Potts fast path (unnormalized, exact):
//   Tmin_s = min_l T_s(l);  Q_s = Tmin_s + c
//   T_{s+1}(l) = u_{s+1}(l) + min(T_s(l), Q_s)
//   m_{s+1}(l) = min(T_s(l), Q_s) - Tmin_s          (m_0 = 0)
// ---------------------------------------------------------------------------
template<bool FIRST>
__global__ __launch_bounds__(64) void sweep_kernel(
    const _Float16* __restrict__ tot, const float* __restrict__ ctx,
    unsigned char* __restrict__ msgs, float* __restrict__ scales)
{
    // one pool, two overlays (potts-staging vs general path; never both live)
    __shared__ __align__(16) unsigned char pool[11648];
    auto ltot = (unsigned char (*)[8][416])pool;            // [2][8][416] 6656
    auto lmsg = (unsigned char (*)[8][208])(pool + 6656);   // [2][8][208] 3328
    auto lout = (unsigned char (*)[208])(pool + 9984);      // [8][208]    1664
    float* shc  = (float*)pool;                             // 441 f  (general)
    float* shrm = (float*)(pool + 1792);                    // 21 f   (general)
    auto   sht  = (float (*)[24])(pool + 1920);             // 8x24 f (general)

    const int lane = threadIdx.x;
    const int g = lane >> 3, k = lane & 7;
    const bool hz = (blockIdx.x < 1024);

    int d, chunk, r;                 // r = line index (row for hz, col-id for v)
    int tstr, mstr;                  // per-step strides (elements / bytes)
    size_t pbase;                    // first-pixel index of the full line
    if (hz) {
        int cl = blockIdx.x * 8 + g;         // [0, 8192)
        chunk = cl >> 11;                    // 0..3  (2048 lines/chunk, %8==0)
        int line = cl & 2047;
        d = line >> 10;                      // 0 or 1
        r = line & 1023;                     // b*H + h
        pbase = (size_t)r * WW;
        tstr = TSL; mstr = MSL;
        if (d == 1) { pbase += WW - 1; tstr = -tstr; mstr = -mstr; }
    } else {
        int cl = (blockIdx.x - 1024) * 8 + g;  // [0, 16384)
        chunk = cl >> 12;                    // 0..3  (4096 lines/chunk, %8==0)
        int line = cl & 4095;
        d = 2 + (line >> 11);                // 2 or 3
        r = line & 2047;
        int bb = r >> 9, w = r & 511;
        pbase = (size_t)bb * HH * WW + w;
        tstr = WW * TSL; mstr = WW * MSL;
        if (d == 3) { pbase += (size_t)(HH - 1) * WW; tstr = -tstr; mstr = -mstr; }
    }
    const int CL = hz ? CH : CHV;                        // chunk length
    const int ss = (chunk == 0) ? 0 : HA;                // halo steps
    const int sw = (chunk == 0) ? 0 : chunk * CL - HA;   // start (sweep order)

    const float* ctxd = ctx + d * (LL * LL);
    const float  c    = ctxd[1];          // candidate Potts constant

    // Potts detection + ctx range (lane k scans its columns 4k..4k+3)
    bool bad = (c < 0.f);
    float cmx = -1e30f, cmn = 1e30f;
    #pragma unroll
    for (int e = 0; e < 4; ++e) {
        int j = 4 * k + e;
        if (j < LL) {
            for (int l = 0; l < LL; ++l) {
                float v = ctxd[l * LL + j];
                float want = (l == j) ? 0.f : c;
                if (v != want) bad = true;
                cmx = fmaxf(cmx, v); cmn = fminf(cmn, v);
            }
        }
    }
    const bool potts = (__ballot(bad) == 0ull);
    const float R    = fmaxf(max8(cmx) - min8(cmn), 0.f);
    const float s255 = (R > 0.f) ? 255.f / R : 0.f;
    const float rs   = R * (1.f / 255.f);

    if (FIRST && lane == 0) scales[d] = R;   // same value from every block

    const bool act = (k < 6);
    const int  koff = act ? 4 * k : 0;    // dummies alias lane-0 addresses
    const bool dpos = ((d & 1) == 0);

    if (potts && hz) {
        // ================= horizontal: LDS-staged dense batches ============
        const int r0 = r - g;                       // block's first row
        const int sl = lane & 7;                    // staging line index
        const int lg = lane >> 3;                   // staging granule index
        const char* tlineb = (const char*)tot
                             + (size_t)(r0 + sl) * ((size_t)WW * 48);
        unsigned char* mlineb = msgs + (size_t)d * MFLD
                              + (size_t)(r0 + sl) * ((size_t)WW * 24);

        const int NB  = (ss + CH) / HB;             // 16 or 20 batches
        const int swb = ss / HB;                    // first stored batch

        // staging registers (dense 16-B granules; batch = 8 px/line)
        uvec4 rt0, rt1, rt2;                        // tot: 384 B/line
        uvec4 rm0; uint2 rm1;                       // msg: 192 B/line

        auto wpix = [&](int b) {                    // batch window base pixel
            return dpos ? (sw + HB * b) : ((WW - HB) - sw - HB * b);
        };
        auto issue = [&](int b) {                   // global -> regs (dense)
            int wp = wpix(b);
            const char* tb = tlineb + (size_t)wp * 48;
            rt0 = *(const uvec4*)(tb + lg * 16);
            rt1 = *(const uvec4*)(tb + 128 + lg * 16);
            rt2 = *(const uvec4*)(tb + 256 + lg * 16);
            if (!FIRST) {
                const unsigned char* mq = mlineb + (size_t)wp * 24;
                rm0 = *(const uvec4*)(mq + lg * 16);
                rm1 = *(const uint2*)(mq + 128 + lg * 8);
            }
        };
        auto commit = [&](int b) {                  // regs -> LDS buf (b&1)
            unsigned char* Lt = &ltot[b & 1][sl][0];
            *(uvec4*)(Lt + lg * 16)       = rt0;
            *(uvec4*)(Lt + 128 + lg * 16) = rt1;
            *(uvec4*)(Lt + 256 + lg * 16) = rt2;
            if (!FIRST) {
                unsigned char* Lm = &lmsg[b & 1][sl][0];
                *(uvec4*)(Lm + lg * 16)      = rm0;
                *(uint2*)(Lm + 128 + lg * 8) = rm1;
            }
        };
        auto flushb = [&](int b) {                  // LDS out -> global (dense)
            int wp = wpix(b);
            unsigned char* mq = mlineb + (size_t)wp * 24;
            const unsigned char* Lo = &lout[sl][0];
            uvec4 a = *(const uvec4*)(Lo + lg * 16);
            uint2 bq = *(const uint2*)(Lo + 128 + lg * 8);
            *(uvec4*)(mq + lg * 16)      = a;
            *(uint2*)(mq + 128 + lg * 8) = bq;
        };

        float mn0 = 0.f, mn1 = 0.f, mn2 = 0.f, mn3 = 0.f, tminp = 0.f;

        issue(0); commit(0);
        issue(1);
        for (int b = 0; b < NB; ++b) {
            const bool st = (b >= swb);

            // hoist the whole window into regs: chain below is pure-register
            hvec4 th8[HB]; unsigned wd8[HB];
            {
                const unsigned char* Lt = &ltot[b & 1][g][0];
                const unsigned char* Lm = &lmsg[b & 1][g][0];
                #pragma unroll
                for (int i = 0; i < HB; ++i) {
                    int p = dpos ? i : HB - 1 - i;
                    th8[i] = *(const hvec4*)(Lt + p * 48 + 2 * koff);
                    wd8[i] = FIRST ? 0u : *(const unsigned*)(Lm + p * 24 + koff);
                }
            }
            if (b + 1 < NB) commit(b + 1);
            if (b + 2 < NB) issue(b + 2);

            #pragma unroll
            for (int i = 0; i < HB; ++i) {
                int p = dpos ? i : HB - 1 - i;
                // quantize state BEFORE consuming this pixel (side ops)
                if (st && act) {
                    float off = fmaf(-tminp, s255, 0.5f);
                    unsigned q0 = (unsigned)fmaf(mn0, s255, off);
                    unsigned q1 = (unsigned)fmaf(mn1, s255, off);
                    unsigned q2 = (unsigned)fmaf(mn2, s255, off);
                    unsigned q3 = (unsigned)fmaf(mn3, s255, off);
                    *(unsigned*)(&lout[g][0] + p * 24 + 4 * k) =
                        q0 | (q1 << 8) | (q2 << 16) | (q3 << 24);
                }
                hvec4 th = th8[i]; unsigned wd = wd8[i];
                float T0, T1, T2, T3;
                if (FIRST) {
                    T0 = (float)th[0] + mn0; T1 = (float)th[1] + mn1;
                    T2 = (float)th[2] + mn2; T3 = (float)th[3] + mn3;
                } else {
                    T0 = fmaf(-rs, (float)( wd        & 0xffu), (float)th[0]) + mn0;
                    T1 = fmaf(-rs, (float)((wd >>  8) & 0xffu), (float)th[1]) + mn1;
                    T2 = fmaf(-rs, (float)((wd >> 16) & 0xffu), (float)th[2]) + mn2;
                    T3 = fmaf(-rs, (float)( wd >> 24        ), (float)th[3]) + mn3;
                }
                float lm = fminf(fminf(T0, T1), fminf(T2, T3));
                lm = min8(lm);
                float Q = lm + c;
                mn0 = fminf(T0, Q); mn1 = fminf(T1, Q);
                mn2 = fminf(T2, Q); mn3 = fminf(T3, Q);
                tminp = lm;
            }
            if (st) flushb(b);
        }
    } else if (potts) {
        // ================= vertical: register FIFO (FDV=16) ================
        const _Float16* tp = tot + pbase * TSL + koff + (ptrdiff_t)sw * tstr;
        unsigned char*  mb = msgs + (size_t)d * MFLD + pbase * MSL + koff
                                  + (ptrdiff_t)sw * mstr;

        hvec4 tf[FDV]; unsigned mfq[FDV];
        #pragma unroll
        for (int i = 0; i < FDV; ++i) {
            tf[i] = *(const hvec4*)(tp + (ptrdiff_t)i * tstr);
            mfq[i] = FIRST ? 0u : *(const unsigned*)(mb + (ptrdiff_t)i * mstr);
        }
        const _Float16* tld = tp + (ptrdiff_t)FDV * tstr;
        const unsigned char* mld = mb + (ptrdiff_t)FDV * mstr;
        unsigned char* mst = mb;

        float mn0 = 0.f, mn1 = 0.f, mn2 = 0.f, mn3 = 0.f, tminp = 0.f;

        auto vstep = [&](hvec4 th, unsigned wd, bool st) {
            if (st && act) {
                float off = fmaf(-tminp, s255, 0.5f);
                unsigned q0 = (unsigned)fmaf(mn0, s255, off);
                unsigned q1 = (unsigned)fmaf(mn1, s255, off);
                unsigned q2 = (unsigned)fmaf(mn2, s255, off);
                unsigned q3 = (unsigned)fmaf(mn3, s255, off);
                *(unsigned*)mst = q0 | (q1 << 8) | (q2 << 16) | (q3 << 24);
            }
            mst += mstr;
            float T0, T1, T2, T3;
            if (FIRST) {
                T0 = (float)th[0] + mn0; T1 = (float)th[1] + mn1;
                T2 = (float)th[2] + mn2; T3 = (float)th[3] + mn3;
            } else {
                T0 = fmaf(-rs, (float)( wd        & 0xffu), (float)th[0]) + mn0;
                T1 = fmaf(-rs, (float)((wd >>  8) & 0xffu), (float)th[1]) + mn1;
                T2 = fmaf(-rs, (float)((wd >> 16) & 0xffu), (float)th[2]) + mn2;
                T3 = fmaf(-rs, (float)( wd >> 24        ), (float)th[3]) + mn3;
            }
            float lm = fminf(fminf(T0, T1), fminf(T2, T3));
            lm = min8(lm);
            float Q = lm + c;
            mn0 = fminf(T0, Q); mn1 = fminf(T1, Q);
            mn2 = fminf(T2, Q); mn3 = fminf(T3, Q);
            tminp = lm;
        };

        const int nout = (ss + CHV - FDV) / FDV;     // 3 or 5
        for (int j = 0; j < nout; ++j) {
            const bool st = (FDV * j >= ss);
            #pragma unroll
            for (int i = 0; i < FDV; ++i) {
                hvec4 th = tf[i]; unsigned wd = mfq[i];
                tf[i] = *(const hvec4*)tld;
                if (!FIRST) mfq[i] = *(const unsigned*)mld;
                tld += tstr; mld += mstr;
                vstep(th, wd, st);
            }
        }
        #pragma unroll
        for (int i = 0; i < FDV; ++i) vstep(tf[i], mfq[i], true);
    } else {
        // ========== general min-plus path (arbitrary ctx; cold) ============
        for (int i = lane; i < LL * LL; i += 64) shc[i] = ctxd[i];
        __syncthreads();
        if (lane < LL) {
            float mn = shc[lane * LL];
            for (int j = 1; j < LL; ++j) mn = fminf(mn, shc[lane * LL + j]);
            shrm[lane] = mn;
        }
        __syncthreads();

        const bool okA = (k < 6);
        const bool okB = (k < 5);
        const _Float16* tp = tot + pbase * TSL + koff + (ptrdiff_t)sw * tstr;
        const unsigned char* mld = msgs + (size_t)d * MFLD + pbase * MSL + koff
                                        + (ptrdiff_t)sw * mstr;
        unsigned char* mst = (unsigned char*)mld;

        float m0 = 0.f, m1 = 0.f, m2 = 0.f, m3 = 0.f;
        const int j0 = (4 * k     < LL) ? 4 * k     : LL - 1;
        const int j1 = (4 * k + 1 < LL) ? 4 * k + 1 : LL - 1;
        const int j2 = (4 * k + 2 < LL) ? 4 * k + 2 : LL - 1;
        const int j3 = (4 * k + 3 < LL) ? 4 * k + 3 : LL - 1;

        const int total = ss + CL;
        for (int t = 0; t < total; ++t) {
            const bool st = (t >= ss);
            if (st && act) {
                unsigned q0 = (unsigned)fminf(fmaf(m0, s255, 0.5f), 255.f);
                unsigned q1 = (unsigned)fminf(fmaf(m1, s255, 0.5f), 255.f);
                unsigned q2 = (unsigned)fminf(fmaf(m2, s255, 0.5f), 255.f);
                unsigned q3 = (unsigned)fminf(fmaf(m3, s255, 0.5f), 255.f);
                *(unsigned*)mst = q0 | (q1 << 8) | (q2 << 16) | (q3 << 24);
            }
            hvec4 th = *(const hvec4*)(tp + (ptrdiff_t)t * tstr);
            unsigned wd = FIRST ? 0u
                : *(const unsigned*)(mld + (ptrdiff_t)t * mstr);
            mst += mstr;
            float t0, t1, t2, t3;
            if (FIRST) {
                t0 = (float)th[0] + m0; t1 = (float)th[1] + m1;
                t2 = (float)th[2] + m2; t3 = (float)th[3] + m3;
            } else {
                t0 = fmaf(-rs, (float)( wd        & 0xffu), (float)th[0]) + m0;
                t1 = fmaf(-rs, (float)((wd >>  8) & 0xffu), (float)th[1]) + m1;
                t2 = fmaf(-rs, (float)((wd >> 16) & 0xffu), (float)th[2]) + m2;
                t3 = fmaf(-rs, (float)( wd >> 24        ), (float)th[3]) + m3;
            }
            __syncthreads();
            if (okA) sht[g][4 * k] = t0;
            if (okB) {
                sht[g][4 * k + 1] = t1;
                sht[g][4 * k + 2] = t2;
                sht[g][4 * k + 3] = t3;
            }
            __syncthreads();
            float mnA = 1e30f, mnB = 1e30f, mnC = 1e30f, mnD = 1e30f;
            float gm  = 1e30f;
            for (int l = 0; l < LL; ++l) {
                float tl = sht[g][l];
                mnA = fminf(mnA, tl + shc[l * LL + j0]);
                mnB = fminf(mnB, tl + shc[l * LL + j1]);
                mnC = fminf(mnC, tl + shc[l * LL + j2]);
                mnD = fminf(mnD, tl + shc[l * LL + j3]);
                gm  = fminf(gm,  tl + shrm[l]);
            }
            m0 = mnA - gm; m1 = mnB - gm; m2 = mnC - gm; m3 = mnD - gm;
        }
    }
}

// ---------------------------------------------------------------------------
extern "C" void kernel_launch(void* const* d_in, const int* in_sizes, int n_in,
                              void* d_out, int out_size, void* d_ws, size_t ws_size,
                              hipStream_t stream)
{
    (void)in_sizes; (void)n_in; (void)out_size; (void)ws_size;

    const float* phi = (const float*)d_in[0];
    const float* ctx = (const float*)d_in[1];   // [4,21,21]
    float* out = (float*)d_out;                 // packed final output

    unsigned char* msgs = (unsigned char*)d_ws;            // 4 uint8 fields (50.3 MB)
    _Float16* totp = (_Float16*)((char*)d_ws + 4 * MFLD);  // fp16 tot (25.2 MB)
    float* scales  = (float*)((char*)totp + (size_t)PIX * TSL * sizeof(_Float16));

    const int EW_BLOCKS = PIX / 256;            // 2048, exact
    const int SW_BLOCKS = 1024 + 2048;          // hz + vt chunked blocks

    // tot = phi (fp16 padded)
    pad_kernel<<<EW_BLOCKS, 256, 0, stream>>>(phi, totp);

    // iteration 1: old msgs == 0 (never read); writes scales[] for ewise
    sweep_kernel<true><<<SW_BLOCKS, 64, 0, stream>>>(totp, ctx, msgs, scales);

    for (int it = 1; it < 5; ++it) {
        ewise_kernel<<<EW_BLOCKS, 256, 0, stream>>>(phi, msgs, scales,
                                                    nullptr, totp, 1.0f, 1);
        sweep_kernel<false><<<SW_BLOCKS, 64, 0, stream>>>(totp, ctx, msgs, scales);
    }

    // final belief: phi*GAMMA_MNODE + sum of messages (packed fp32 to d_out)
    ewise_kernel<<<EW_BLOCKS, 256, 0, stream>>>(phi, msgs, scales,
                                                out, nullptr, 2.0f, 0);
}

// Round 12
// 395.463 us; speedup vs baseline: 1.0943x; 1.0353x over previous
//
#include <hip/hip_runtime.h>

// Problem constants (fixed by setup_inputs)
#define BB 4
#define HH 256
#define WW 512
#define LL 21
#define PIX (BB*HH*WW)            // 524288 pixels
#define MSL 24                    // uint8 labels per pixel (24 B rows)
#define TSL 24                    // fp16 labels per pixel  (48 B rows)
#define MFLD ((size_t)PIX*MSL)    // bytes per direction's msg field
#define PADV 1000.0f              // pad-label value: self-sanitizing (never min)

// Chunked scanlines, HA=32-pixel m=0 warm-up halo (not stored).
// *** CORRECTNESS CONSTRAINT (R9/R11 post-mortem): total sweep blocks must be
// *** <= co-resident capacity (LDS 11.6KB -> 13 blocks/CU -> 3328; proven 3072).
// *** In-place msgs: halo prefetch must read PREV-iteration values (they were
// *** summed into tot); late-started overflow blocks read new values -> absmax
// *** 1.5 (R9: 5120 blocks FAIL; R11: 4096 FAIL; 3072 PASS R7/R8/R10).
// Horizontal (S=512): CH=128  -> 4 chunks x 2048 lines = 8192 cl -> 1024 blocks.
// Vertical   (S=256): CHV=128 -> 2 chunks x 4096 lines = 8192 cl -> 1024 blocks.
// 2048 blocks, ALL 160-step (chunk-0: 128) -> balanced, no drain tail.
#define CH 128
#define CHV 128
#define HA 32
#define FDV 16                    // vt FIFO: 32 loads + 16 stores = 48 <= 63
#define HB 8                      // horizontal batch steps (LDS-staged)

typedef float    fvec4 __attribute__((ext_vector_type(4)));
typedef _Float16 hvec4 __attribute__((ext_vector_type(4)));
typedef _Float16 hvec8 __attribute__((ext_vector_type(8)));
typedef unsigned uvec4 __attribute__((ext_vector_type(4)));

__device__ __forceinline__ fvec4 load4u(const float* p) {
    fvec4 v; __builtin_memcpy(&v, p, 16); return v;
}
__device__ __forceinline__ void store4u(float* p, fvec4 v) {
    __builtin_memcpy(p, &v, 16);
}

// ---------------------------------------------------------------------------
// pad: tot = phi, fp16 padded-24 (pads = PADV). One pixel per thread.
// ---------------------------------------------------------------------------
__global__ __launch_bounds__(256) void pad_kernel(
    const float* __restrict__ phi, _Float16* __restrict__ tot)
{
    int p = blockIdx.x * 256 + threadIdx.x;      // < PIX
    const float* pp = phi + (size_t)p * LL;
    float r[24];
    fvec4 u0 = load4u(pp + 0), u1 = load4u(pp + 4), u2 = load4u(pp + 8);
    fvec4 u3 = load4u(pp + 12), u4 = load4u(pp + 16);
    #pragma unroll
    for (int e = 0; e < 4; ++e) {
        r[e] = u0[e]; r[4+e] = u1[e]; r[8+e] = u2[e];
        r[12+e] = u3[e]; r[16+e] = u4[e];
    }
    r[20] = pp[20];
    r[21] = r[22] = r[23] = PADV;

    _Float16* op = tot + (size_t)p * TSL;
    #pragma unroll
    for (int c3 = 0; c3 < 3; ++c3) {
        hvec8 h;
        #pragma unroll
        for (int e = 0; e < 8; ++e) h[e] = (_Float16)r[8*c3 + e];
        *(hvec8*)(op + 8*c3) = h;
    }
}

// ---------------------------------------------------------------------------
// Elementwise: r = phi*scale + sum_d decode(msg_d).
// padded_out=1 -> fp16 padded-24 tot scratch (pads = PADV); 0 -> packed fp32.
// ---------------------------------------------------------------------------
__global__ __launch_bounds__(256) void ewise_kernel(
    const float* __restrict__ phi, const unsigned char* __restrict__ msgs,
    const float* __restrict__ scales,
    float* __restrict__ outf, _Float16* __restrict__ outh,
    float scale, int padded_out)
{
    int p = blockIdx.x * 256 + threadIdx.x;      // < PIX
    const float* pp = phi + (size_t)p * LL;

    float r[24];
    {
        fvec4 u0 = load4u(pp + 0), u1 = load4u(pp + 4), u2 = load4u(pp + 8);
        fvec4 u3 = load4u(pp + 12), u4 = load4u(pp + 16);
        #pragma unroll
        for (int e = 0; e < 4; ++e) {
            r[e]      = u0[e] * scale;
            r[4 + e]  = u1[e] * scale;
            r[8 + e]  = u2[e] * scale;
            r[12 + e] = u3[e] * scale;
            r[16 + e] = u4[e] * scale;
        }
        r[20] = pp[20] * scale;
        r[21] = r[22] = r[23] = 0.f;
    }

    fvec4 sc = load4u(scales);                   // per-dir ranges R

    #pragma unroll
    for (int d = 0; d < 4; ++d) {
        const unsigned* mp =
            (const unsigned*)(msgs + (size_t)d * MFLD + (size_t)p * MSL);
        uint2 w0 = *(const uint2*)(mp + 0);      // rows are 8-B aligned
        uint2 w1 = *(const uint2*)(mp + 2);
        uint2 w2 = *(const uint2*)(mp + 4);
        unsigned w[6] = { w0.x, w0.y, w1.x, w1.y, w2.x, w2.y };
        float rs = sc[d] * (1.f / 255.f);
        #pragma unroll
        for (int j = 0; j < 21; ++j)
            r[j] += (float)((w[j >> 2] >> ((j & 3) * 8)) & 0xffu) * rs;
    }

    if (padded_out) {
        _Float16* op = outh + (size_t)p * TSL;
        r[21] = r[22] = r[23] = PADV;
        #pragma unroll
        for (int c3 = 0; c3 < 3; ++c3) {
            hvec8 h;
            #pragma unroll
            for (int e = 0; e < 8; ++e) h[e] = (_Float16)r[8*c3 + e];
            *(hvec8*)(op + 8*c3) = h;
        }
    } else {
        float* op = outf + (size_t)p * LL;
        store4u(op + 0,  *(const fvec4*)(r + 0));
        store4u(op + 4,  *(const fvec4*)(r + 4));
        store4u(op + 8,  *(const fvec4*)(r + 8));
        store4u(op + 12, *(const fvec4*)(r + 12));
        store4u(op + 16, *(const fvec4*)(r + 16));
        op[20] = r[20];
    }
}

// ---------------------------------------------------------------------------
// 8-lane-group min/max (broadcast to all 8 lanes), pure DPP — no DS pipe.
// ---------------------------------------------------------------------------
__device__ __forceinline__ float min8(float x)
{
    int xi = __float_as_int(x); int y;
    y = __builtin_amdgcn_update_dpp(xi, xi, 0xB1, 0xf, 0xf, false);
    x = fminf(x, __int_as_float(y)); xi = __float_as_int(x);
    y = __builtin_amdgcn_update_dpp(xi, xi, 0x4E, 0xf, 0xf, false);
    x = fminf(x, __int_as_float(y)); xi = __float_as_int(x);
    y = __builtin_amdgcn_update_dpp(xi, xi, 0x141, 0xf, 0xf, false);
    x = fminf(x, __int_as_float(y));
    return x;
}
__device__ __forceinline__ float max8(float x)
{
    int xi = __float_as_int(x); int y;
    y = __builtin_amdgcn_update_dpp(xi, xi, 0xB1, 0xf, 0xf, false);
    x = fmaxf(x, __int_as_float(y)); xi = __float_as_int(x);
    y = __builtin_amdgcn_update_dpp(xi, xi, 0x4E, 0xf, 0xf, false);
    x = fmaxf(x, __int_as_float(y)); xi = __float_as_int(x);
    y = __builtin_amdgcn_update_dpp(xi, xi, 0x141, 0xf, 0xf, false);
    x = fmaxf(x, __int_as_float(y));
    return x;
}

// ---------------------------------------------------------------------------
// Directional sweep. One chunk-line per 8-lane group; d, chunk block-uniform.
// blocks [0,1024): horizontal (d 0/1, CH=128); [1024,2048): vertical (d 2/3,
// CHV=128). All blocks run 160 steps (chunk-0: 128) — balanced durations.
//
// hz: LDS double-buffered dense batches; per-batch th8/wd8 register hoist.
// vt: register FIFO, FDV=16 (48 outstanding vmem <= vmcnt window).
//
// Potts fast path (unnormalized, exact):
//   Tmin_s = min_l T_s(l);  Q_s = Tmin_s + c
//   T_{s+1}(l) = u_{s+1}(l) + min(T_s(l), Q_s)
//   m_{s+1}(l) = min(T_s(l), Q_s) - Tmin_s          (m_0 = 0)
// Pad labels carry PADV: pads never win a min (validated R8/R10).
// ---------------------------------------------------------------------------
template<bool FIRST>
__global__ __launch_bounds__(64) void sweep_kernel(
    const _Float16* __restrict__ tot, const float* __restrict__ ctx,
    unsigned char* __restrict__ msgs, float* __restrict__ scales)
{
    // one pool, two overlays (potts-staging vs general path; never both live)
    __shared__ __align__(16) unsigned char pool[11648];
    auto ltot = (unsigned char (*)[8][416])pool;            // [2][8][416] 6656
    auto lmsg = (unsigned char (*)[8][208])(pool + 6656);   // [2][8][208] 3328
    auto lout = (unsigned char (*)[208])(pool + 9984);      // [8][208]    1664
    float* shc  = (float*)pool;                             // 441 f  (general)
    float* shrm = (float*)(pool + 1792);                    // 21 f   (general)
    auto   sht  = (float (*)[24])(pool + 1920);             // 8x24 f (general)

    const int lane = threadIdx.x;
    const int g = lane >> 3, k = lane & 7;
    const bool hz = (blockIdx.x < 1024);

    int d, chunk, r;                 // r = line index (row for hz, col-id for v)
    int tstr, mstr;                  // per-step strides (elements / bytes)
    size_t pbase;                    // first-pixel index of the full line
    if (hz) {
        int cl = blockIdx.x * 8 + g;         // [0, 8192)
        chunk = cl >> 11;                    // 0..3  (2048 lines/chunk, %8==0)
        int line = cl & 2047;
        d = line >> 10;                      // 0 or 1
        r = line & 1023;                     // b*H + h
        pbase = (size_t)r * WW;
        tstr = TSL; mstr = MSL;
        if (d == 1) { pbase += WW - 1; tstr = -tstr; mstr = -mstr; }
    } else {
        int cl = (blockIdx.x - 1024) * 8 + g;  // [0, 8192)
        chunk = cl >> 12;                    // 0..1  (4096 lines/chunk, %8==0)
        int line = cl & 4095;
        d = 2 + (line >> 11);                // 2 or 3
        r = line & 2047;
        int bb = r >> 9, w = r & 511;
        pbase = (size_t)bb * HH * WW + w;
        tstr = WW * TSL; mstr = WW * MSL;
        if (d == 3) { pbase += (size_t)(HH - 1) * WW; tstr = -tstr; mstr = -mstr; }
    }
    const int CL = hz ? CH : CHV;                        // chunk length
    const int ss = (chunk == 0) ? 0 : HA;                // halo steps
    const int sw = (chunk == 0) ? 0 : chunk * CL - HA;   // start (sweep order)

    const float* ctxd = ctx + d * (LL * LL);
    const float  c    = ctxd[1];          // candidate Potts constant

    // Potts detection + ctx range (lane k scans its columns 4k..4k+3)
    bool bad = (c < 0.f);
    float cmx = -1e30f, cmn = 1e30f;
    #pragma unroll
    for (int e = 0; e < 4; ++e) {
        int j = 4 * k + e;
        if (j < LL) {
            for (int l = 0; l < LL; ++l) {
                float v = ctxd[l * LL + j];
                float want = (l == j) ? 0.f : c;
                if (v != want) bad = true;
                cmx = fmaxf(cmx, v); cmn = fminf(cmn, v);
            }
        }
    }
    const bool potts = (__ballot(bad) == 0ull);
    const float R    = fmaxf(max8(cmx) - min8(cmn), 0.f);
    const float s255 = (R > 0.f) ? 255.f / R : 0.f;
    const float rs   = R * (1.f / 255.f);

    if (FIRST && lane == 0) scales[d] = R;   // same value from every block

    const bool act = (k < 6);
    const int  koff = act ? 4 * k : 0;    // dummies alias lane-0 addresses
    const bool dpos = ((d & 1) == 0);

    if (potts && hz) {
        // ================= horizontal: LDS-staged dense batches ============
        const int r0 = r - g;                       // block's first row
        const int sl = lane & 7;                    // staging line index
        const int lg = lane >> 3;                   // staging granule index
        const char* tlineb = (const char*)tot
                             + (size_t)(r0 + sl) * ((size_t)WW * 48);
        unsigned char* mlineb = msgs + (size_t)d * MFLD
                              + (size_t)(r0 + sl) * ((size_t)WW * 24);

        const int NB  = (ss + CH) / HB;             // 16 or 20 batches
        const int swb = ss / HB;                    // first stored batch

        // staging registers (dense 16-B granules; batch = 8 px/line)
        uvec4 rt0, rt1, rt2;                        // tot: 384 B/line
        uvec4 rm0; uint2 rm1;                       // msg: 192 B/line

        auto wpix = [&](int b) {                    // batch window base pixel
            return dpos ? (sw + HB * b) : ((WW - HB) - sw - HB * b);
        };
        auto issue = [&](int b) {                   // global -> regs (dense)
            int wp = wpix(b);
            const char* tb = tlineb + (size_t)wp * 48;
            rt0 = *(const uvec4*)(tb + lg * 16);
            rt1 = *(const uvec4*)(tb + 128 + lg * 16);
            rt2 = *(const uvec4*)(tb + 256 + lg * 16);
            if (!FIRST) {
                const unsigned char* mq = mlineb + (size_t)wp * 24;
                rm0 = *(const uvec4*)(mq + lg * 16);
                rm1 = *(const uint2*)(mq + 128 + lg * 8);
            }
        };
        auto commit = [&](int b) {                  // regs -> LDS buf (b&1)
            unsigned char* Lt = &ltot[b & 1][sl][0];
            *(uvec4*)(Lt + lg * 16)       = rt0;
            *(uvec4*)(Lt + 128 + lg * 16) = rt1;
            *(uvec4*)(Lt + 256 + lg * 16) = rt2;
            if (!FIRST) {
                unsigned char* Lm = &lmsg[b & 1][sl][0];
                *(uvec4*)(Lm + lg * 16)      = rm0;
                *(uint2*)(Lm + 128 + lg * 8) = rm1;
            }
        };
        auto flushb = [&](int b) {                  // LDS out -> global (dense)
            int wp = wpix(b);
            unsigned char* mq = mlineb + (size_t)wp * 24;
            const unsigned char* Lo = &lout[sl][0];
            uvec4 a = *(const uvec4*)(Lo + lg * 16);
            uint2 bq = *(const uint2*)(Lo + 128 + lg * 8);
            *(uvec4*)(mq + lg * 16)      = a;
            *(uint2*)(mq + 128 + lg * 8) = bq;
        };

        float mn0 = 0.f, mn1 = 0.f, mn2 = 0.f, mn3 = 0.f, tminp = 0.f;

        issue(0); commit(0);
        issue(1);
        for (int b = 0; b < NB; ++b) {
            const bool st = (b >= swb);

            // hoist the whole window into regs: chain below is pure-register
            hvec4 th8[HB]; unsigned wd8[HB];
            {
                const unsigned char* Lt = &ltot[b & 1][g][0];
                const unsigned char* Lm = &lmsg[b & 1][g][0];
                #pragma unroll
                for (int i = 0; i < HB; ++i) {
                    int p = dpos ? i : HB - 1 - i;
                    th8[i] = *(const hvec4*)(Lt + p * 48 + 2 * koff);
                    wd8[i] = FIRST ? 0u : *(const unsigned*)(Lm + p * 24 + koff);
                }
            }
            if (b + 1 < NB) commit(b + 1);
            if (b + 2 < NB) issue(b + 2);

            #pragma unroll
            for (int i = 0; i < HB; ++i) {
                int p = dpos ? i : HB - 1 - i;
                // quantize state BEFORE consuming this pixel (side ops)
                if (st && act) {
                    float off = fmaf(-tminp, s255, 0.5f);
                    unsigned q0 = (unsigned)fmaf(mn0, s255, off);
                    unsigned q1 = (unsigned)fmaf(mn1, s255, off);
                    unsigned q2 = (unsigned)fmaf(mn2, s255, off);
                    unsigned q3 = (unsigned)fmaf(mn3, s255, off);
                    *(unsigned*)(&lout[g][0] + p * 24 + 4 * k) =
                        q0 | (q1 << 8) | (q2 << 16) | (q3 << 24);
                }
                hvec4 th = th8[i]; unsigned wd = wd8[i];
                float T0, T1, T2, T3;
                if (FIRST) {
                    T0 = (float)th[0] + mn0; T1 = (float)th[1] + mn1;
                    T2 = (float)th[2] + mn2; T3 = (float)th[3] + mn3;
                } else {
                    T0 = fmaf(-rs, (float)( wd        & 0xffu), (float)th[0]) + mn0;
                    T1 = fmaf(-rs, (float)((wd >>  8) & 0xffu), (float)th[1]) + mn1;
                    T2 = fmaf(-rs, (float)((wd >> 16) & 0xffu), (float)th[2]) + mn2;
                    T3 = fmaf(-rs, (float)( wd >> 24        ), (float)th[3]) + mn3;
                }
                float lm = fminf(fminf(T0, T1), fminf(T2, T3));
                lm = min8(lm);
                float Q = lm + c;
                mn0 = fminf(T0, Q); mn1 = fminf(T1, Q);
                mn2 = fminf(T2, Q); mn3 = fminf(T3, Q);
                tminp = lm;
            }
            if (st) flushb(b);
        }
    } else if (potts) {
        // ================= vertical: register FIFO (FDV=16) ================
        const _Float16* tp = tot + pbase * TSL + koff + (ptrdiff_t)sw * tstr;
        unsigned char*  mb = msgs + (size_t)d * MFLD + pbase * MSL + koff
                                  + (ptrdiff_t)sw * mstr;

        hvec4 tf[FDV]; unsigned mfq[FDV];
        #pragma unroll
        for (int i = 0; i < FDV; ++i) {
            tf[i] = *(const hvec4*)(tp + (ptrdiff_t)i * tstr);
            mfq[i] = FIRST ? 0u : *(const unsigned*)(mb + (ptrdiff_t)i * mstr);
        }
        const _Float16* tld = tp + (ptrdiff_t)FDV * tstr;
        const unsigned char* mld = mb + (ptrdiff_t)FDV * mstr;
        unsigned char* mst = mb;

        float mn0 = 0.f, mn1 = 0.f, mn2 = 0.f, mn3 = 0.f, tminp = 0.f;

        auto vstep = [&](hvec4 th, unsigned wd, bool st) {
            if (st && act) {
                float off = fmaf(-tminp, s255, 0.5f);
                unsigned q0 = (unsigned)fmaf(mn0, s255, off);
                unsigned q1 = (unsigned)fmaf(mn1, s255, off);
                unsigned q2 = (unsigned)fmaf(mn2, s255, off);
                unsigned q3 = (unsigned)fmaf(mn3, s255, off);
                *(unsigned*)mst = q0 | (q1 << 8) | (q2 << 16) | (q3 << 24);
            }
            mst += mstr;
            float T0, T1, T2, T3;
            if (FIRST) {
                T0 = (float)th[0] + mn0; T1 = (float)th[1] + mn1;
                T2 = (float)th[2] + mn2; T3 = (float)th[3] + mn3;
            } else {
                T0 = fmaf(-rs, (float)( wd        & 0xffu), (float)th[0]) + mn0;
                T1 = fmaf(-rs, (float)((wd >>  8) & 0xffu), (float)th[1]) + mn1;
                T2 = fmaf(-rs, (float)((wd >> 16) & 0xffu), (float)th[2]) + mn2;
                T3 = fmaf(-rs, (float)( wd >> 24        ), (float)th[3]) + mn3;
            }
            float lm = fminf(fminf(T0, T1), fminf(T2, T3));
            lm = min8(lm);
            float Q = lm + c;
            mn0 = fminf(T0, Q); mn1 = fminf(T1, Q);
            mn2 = fminf(T2, Q); mn3 = fminf(T3, Q);
            tminp = lm;
        };

        const int nout = (ss + CHV - FDV) / FDV;     // 7 or 9
        for (int j = 0; j < nout; ++j) {
            const bool st = (FDV * j >= ss);
            #pragma unroll
            for (int i = 0; i < FDV; ++i) {
                hvec4 th = tf[i]; unsigned wd = mfq[i];
                tf[i] = *(const hvec4*)tld;
                if (!FIRST) mfq[i] = *(const unsigned*)mld;
                tld += tstr; mld += mstr;
                vstep(th, wd, st);
            }
        }
        #pragma unroll
        for (int i = 0; i < FDV; ++i) vstep(tf[i], mfq[i], true);
    } else {
        // ========== general min-plus path (arbitrary ctx; cold) ============
        for (int i = lane; i < LL * LL; i += 64) shc[i] = ctxd[i];
        __syncthreads();
        if (lane < LL) {
            float mn = shc[lane * LL];
            for (int j = 1; j < LL; ++j) mn = fminf(mn, shc[lane * LL + j]);
            shrm[lane] = mn;
        }
        __syncthreads();

        const bool okA = (k < 6);
        const bool okB = (k < 5);
        const _Float16* tp = tot + pbase * TSL + koff + (ptrdiff_t)sw * tstr;
        const unsigned char* mld = msgs + (size_t)d * MFLD + pbase * MSL + koff
                                        + (ptrdiff_t)sw * mstr;
        unsigned char* mst = (unsigned char*)mld;

        float m0 = 0.f, m1 = 0.f, m2 = 0.f, m3 = 0.f;
        const int j0 = (4 * k     < LL) ? 4 * k     : LL - 1;
        const int j1 = (4 * k + 1 < LL) ? 4 * k + 1 : LL - 1;
        const int j2 = (4 * k + 2 < LL) ? 4 * k + 2 : LL - 1;
        const int j3 = (4 * k + 3 < LL) ? 4 * k + 3 : LL - 1;

        const int total = ss + CL;
        for (int t = 0; t < total; ++t) {
            const bool st = (t >= ss);
            if (st && act) {
                unsigned q0 = (unsigned)fminf(fmaf(m0, s255, 0.5f), 255.f);
                unsigned q1 = (unsigned)fminf(fmaf(m1, s255, 0.5f), 255.f);
                unsigned q2 = (unsigned)fminf(fmaf(m2, s255, 0.5f), 255.f);
                unsigned q3 = (unsigned)fminf(fmaf(m3, s255, 0.5f), 255.f);
                *(unsigned*)mst = q0 | (q1 << 8) | (q2 << 16) | (q3 << 24);
            }
            hvec4 th = *(const hvec4*)(tp + (ptrdiff_t)t * tstr);
            unsigned wd = FIRST ? 0u
                : *(const unsigned*)(mld + (ptrdiff_t)t * mstr);
            mst += mstr;
            float t0, t1, t2, t3;
            if (FIRST) {
                t0 = (float)th[0] + m0; t1 = (float)th[1] + m1;
                t2 = (float)th[2] + m2; t3 = (float)th[3] + m3;
            } else {
                t0 = fmaf(-rs, (float)( wd        & 0xffu), (float)th[0]) + m0;
                t1 = fmaf(-rs, (float)((wd >>  8) & 0xffu), (float)th[1]) + m1;
                t2 = fmaf(-rs, (float)((wd >> 16) & 0xffu), (float)th[2]) + m2;
                t3 = fmaf(-rs, (float)( wd >> 24        ), (float)th[3]) + m3;
            }
            __syncthreads();
            if (okA) sht[g][4 * k] = t0;
            if (okB) {
                sht[g][4 * k + 1] = t1;
                sht[g][4 * k + 2] = t2;
                sht[g][4 * k + 3] = t3;
            }
            __syncthreads();
            float mnA = 1e30f, mnB = 1e30f, mnC = 1e30f, mnD = 1e30f;
            float gm  = 1e30f;
            for (int l = 0; l < LL; ++l) {
                float tl = sht[g][l];
                mnA = fminf(mnA, tl + shc[l * LL + j0]);
                mnB = fminf(mnB, tl + shc[l * LL + j1]);
                mnC = fminf(mnC, tl + shc[l * LL + j2]);
                mnD = fminf(mnD, tl + shc[l * LL + j3]);
                gm  = fminf(gm,  tl + shrm[l]);
            }
            m0 = mnA - gm; m1 = mnB - gm; m2 = mnC - gm; m3 = mnD - gm;
        }
    }
}

// ---------------------------------------------------------------------------
extern "C" void kernel_launch(void* const* d_in, const int* in_sizes, int n_in,
                              void* d_out, int out_size, void* d_ws, size_t ws_size,
                              hipStream_t stream)
{
    (void)in_sizes; (void)n_in; (void)out_size; (void)ws_size;

    const float* phi = (const float*)d_in[0];
    const float* ctx = (const float*)d_in[1];   // [4,21,21]
    float* out = (float*)d_out;                 // packed final output

    unsigned char* msgs = (unsigned char*)d_ws;            // 4 uint8 fields (50.3 MB)
    _Float16* totp = (_Float16*)((char*)d_ws + 4 * MFLD);  // fp16 tot (25.2 MB)
    float* scales  = (float*)((char*)totp + (size_t)PIX * TSL * sizeof(_Float16));

    const int EW_BLOCKS = PIX / 256;            // 2048, exact
    const int SW_BLOCKS = 1024 + 1024;          // hz + vt, balanced 160-step blocks

    // tot = phi (fp16 padded)
    pad_kernel<<<EW_BLOCKS, 256, 0, stream>>>(phi, totp);

    // iteration 1: old msgs == 0 (never read); writes scales[] for ewise
    sweep_kernel<true><<<SW_BLOCKS, 64, 0, stream>>>(totp, ctx, msgs, scales);

    for (int it = 1; it < 5; ++it) {
        ewise_kernel<<<EW_BLOCKS, 256, 0, stream>>>(phi, msgs, scales,
                                                    nullptr, totp, 1.0f, 1);
        sweep_kernel<false><<<SW_BLOCKS, 64, 0, stream>>>(totp, ctx, msgs, scales);
    }

    // final belief: phi*GAMMA_MNODE + sum of messages (packed fp32 to d_out)
    ewise_kernel<<<EW_BLOCKS, 256, 0, stream>>>(phi, msgs, scales,
                                                out, nullptr, 2.0f, 0);
}